// Round 1
// baseline (492.143 us; speedup 1.0000x reference)
//
#include <hip/hip_runtime.h>
#include <math.h>

#define Bn 64
#define An 5
#define Cn 80
#define Hn 52
#define Wn 52
#define Tn 32
#define HWn (Hn * Wn)

__device__ __forceinline__ float softplusf_(float x) {
    // stable: max(x,0) + log1p(exp(-|x|))
    return fmaxf(x, 0.f) + log1pf(expf(-fabsf(x)));
}

__device__ __forceinline__ float sigmoidf_(float x) {
    return 1.f / (1.f + expf(-x));
}

// IoU of predicted box (raw pb0,pb1,pw,ph at cell (h,w)) vs target box [gx1,gy1,gx2,gy2] with area tarea
__device__ __forceinline__ float iou_cell(float pb0, float pb1, float pw, float ph,
                                          int h, int w,
                                          float gx1, float gy1, float gx2, float gy2,
                                          float tarea) {
    float px1 = sigmoidf_(pb0) + (float)w - pw * 0.5f;
    float py1 = sigmoidf_(pb1) + (float)h - ph * 0.5f;
    float px2 = px1 + pw, py2 = py1 + ph;
    float dx = fmaxf(fminf(px2, gx2) - fmaxf(px1, gx1), 0.f);
    float dy = fmaxf(fminf(py2, gy2) - fmaxf(py1, gy1), 0.f);
    float inter = dx * dy;
    return inter / (pw * ph + tarea - inter);
}

// ws layout (doubles): 0=neg_sum(all neg cells softplus), 1=pos, 2=neg_corr, 3=cls, 4=xy, 5=wh

__global__ void cell_kernel(const float* __restrict__ pred_resp,
                            const float* __restrict__ pred_bb,
                            const float* __restrict__ tgt_box,
                            const int* __restrict__ tix,
                            const int* __restrict__ tiy,
                            double* __restrict__ ws) {
    int idx = blockIdx.x * blockDim.x + threadIdx.x;
    float acc = 0.f;
    if (idx < Bn * An * HWn) {
        int b = idx / (An * HWn);
        int rem = idx - b * (An * HWn);
        int a = rem / HWn;
        int hw = rem - a * HWn;
        int h = hw / Wn;
        int w = hw - h * Wn;
        // target T-1 of batch b (neg_mask uses iou[:, -1] only)
        int tb = b * Tn + (Tn - 1);
        float tx = tgt_box[tb * 4 + 0], ty = tgt_box[tb * 4 + 1];
        float tw = tgt_box[tb * 4 + 2], th = tgt_box[tb * 4 + 3];
        float cx = tx + (float)tix[tb];
        float cy = ty + (float)tiy[tb];
        float gx1 = cx - tw * 0.5f, gy1 = cy - th * 0.5f;
        float gx2 = gx1 + tw, gy2 = gy1 + th;
        const float* pbb = pred_bb + ((size_t)(b * An + a) * 4) * HWn + hw;
        float pb0 = pbb[0];
        float pb1 = pbb[HWn];
        float pw  = pbb[2 * HWn];
        float ph  = pbb[3 * HWn];
        float iou = iou_cell(pb0, pb1, pw, ph, h, w, gx1, gy1, gx2, gy2, tw * th);
        if (iou < 0.6f) acc = softplusf_(pred_resp[idx]);  // gt_response=0 off-target -> bce = softplus
    }
    // block reduction (blockDim.x == 256)
    for (int off = 32; off > 0; off >>= 1) acc += __shfl_down(acc, off);
    __shared__ float s[4];
    int lane = threadIdx.x & 63, wid = threadIdx.x >> 6;
    if (lane == 0) s[wid] = acc;
    __syncthreads();
    if (threadIdx.x == 0) {
        float v = s[0] + s[1] + s[2] + s[3];
        atomicAdd(&ws[0], (double)v);
    }
}

__global__ void target_kernel(const float* __restrict__ pred_cls,
                              const float* __restrict__ pred_resp,
                              const float* __restrict__ pred_bb,
                              const float* __restrict__ tgt_box,
                              const int* __restrict__ tix,
                              const int* __restrict__ tiy,
                              const int* __restrict__ tib,
                              const int* __restrict__ tlab,
                              double* __restrict__ ws) {
    int gwave = (blockIdx.x * blockDim.x + threadIdx.x) >> 6;
    int lane = threadIdx.x & 63;
    if (gwave >= Bn * Tn) return;
    int b = gwave / Tn;
    int t = gwave - b * Tn;
    int tb = b * Tn + t;
    int abox = tib[tb];
    int y = tiy[tb];
    int x = tix[tb];
    int label = tlab[tb];
    float tx = tgt_box[tb * 4 + 0], ty = tgt_box[tb * 4 + 1];
    float tw = tgt_box[tb * 4 + 2], th = tgt_box[tb * 4 + 3];

    // ---- class cross-entropy over Cn=80 logits, one wave ----
    const float* cl = pred_cls + ((size_t)b * (An * Cn) + (size_t)abox * Cn) * HWn + (size_t)y * Wn + x;
    float l0 = cl[(size_t)lane * HWn];                                   // c = lane (0..63, all < 80)
    float l1 = (lane < Cn - 64) ? cl[(size_t)(lane + 64) * HWn] : -INFINITY; // c = lane+64 (64..79)
    float m = fmaxf(l0, l1);
    for (int off = 32; off > 0; off >>= 1) m = fmaxf(m, __shfl_xor(m, off));
    float se = expf(l0 - m) + ((lane < Cn - 64) ? expf(l1 - m) : 0.f);
    for (int off = 32; off > 0; off >>= 1) se += __shfl_xor(se, off);
    float lsel = (label < 64) ? __shfl(l0, label) : __shfl(l1, label - 64);
    float loss_cls = m + logf(se) - lsel;   // = logsumexp - logit[label]

    if (lane == 0) {
        // ---- box / response terms at the target cell ----
        int hw = y * Wn + x;
        const float* pbb = pred_bb + ((size_t)(b * An + abox) * 4) * HWn + hw;
        float pb0 = pbb[0];
        float pb1 = pbb[HWn];
        float pw  = pbb[2 * HWn];
        float ph  = pbb[3 * HWn];
        float r = pred_resp[(size_t)(b * An + abox) * HWn + hw];
        float sp_r = softplusf_(r);

        // iou vs own target box -> gt_response at this (unique) cell
        float cx = tx + (float)x, cy = ty + (float)y;
        float gx1 = cx - tw * 0.5f, gy1 = cy - th * 0.5f;
        float gx2 = gx1 + tw, gy2 = gy1 + th;
        float iou_sel = iou_cell(pb0, pb1, pw, ph, y, x, gx1, gy1, gx2, gy2, tw * th);
        float pos = sp_r - r * iou_sel;  // bce(r, iou_sel), L_OBJ = 1

        // iou vs target T-1 (same expression the cell kernel evaluated) -> neg correction
        int tb31 = b * Tn + (Tn - 1);
        float t31x = tgt_box[tb31 * 4 + 0], t31y = tgt_box[tb31 * 4 + 1];
        float t31w = tgt_box[tb31 * 4 + 2], t31h = tgt_box[tb31 * 4 + 3];
        float c31x = t31x + (float)tix[tb31];
        float c31y = t31y + (float)tiy[tb31];
        float g1x = c31x - t31w * 0.5f, g1y = c31y - t31h * 0.5f;
        float g2x = g1x + t31w, g2y = g1y + t31h;
        float iou31 = iou_cell(pb0, pb1, pw, ph, y, x, g1x, g1y, g2x, g2y, t31w * t31h);
        float negcorr = (iou31 < 0.6f) ? sp_r : 0.f;  // pos cell was counted in cell_kernel's neg sum

        float lxy = (softplusf_(pb0) - pb0 * tx) + (softplusf_(pb1) - pb1 * ty);
        float lwh = (pw - tw) * (pw - tw) + (ph - th) * (ph - th);

        atomicAdd(&ws[1], (double)pos);
        atomicAdd(&ws[2], (double)negcorr);
        atomicAdd(&ws[3], (double)loss_cls);
        atomicAdd(&ws[4], (double)lxy);
        atomicAdd(&ws[5], (double)lwh);
    }
}

__global__ void finalize_kernel(const double* __restrict__ ws, float* __restrict__ out) {
    // out = [loss_pos, loss_neg, loss_cls, loss_xy, loss_wh*L_COORD] / B
    out[0] = (float)(ws[1] / Bn);
    out[1] = (float)(0.5 * (ws[0] - ws[2]) / Bn);   // L_NOOBJ * (neg_all - pos_correction)
    out[2] = (float)(ws[3] / Bn);
    out[3] = (float)(ws[4] / Bn);
    out[4] = (float)(5.0 * ws[5] / Bn);             // L_COORD
}

extern "C" void kernel_launch(void* const* d_in, const int* in_sizes, int n_in,
                              void* d_out, int out_size, void* d_ws, size_t ws_size,
                              hipStream_t stream) {
    const float* pred_cls  = (const float*)d_in[0];
    const float* pred_resp = (const float*)d_in[1];
    const float* pred_bb   = (const float*)d_in[2];
    const float* tgt_box   = (const float*)d_in[3];
    const int*   tix       = (const int*)d_in[4];
    const int*   tiy       = (const int*)d_in[5];
    const int*   tib       = (const int*)d_in[6];
    const int*   tlab      = (const int*)d_in[7];
    double* ws = (double*)d_ws;
    float* out = (float*)d_out;

    hipMemsetAsync(ws, 0, 8 * sizeof(double), stream);

    int ncell = Bn * An * HWn;  // 865,280
    cell_kernel<<<(ncell + 255) / 256, 256, 0, stream>>>(pred_resp, pred_bb, tgt_box, tix, tiy, ws);

    int nthreads = Bn * Tn * 64;  // one wave (64 lanes) per target
    target_kernel<<<(nthreads + 255) / 256, 256, 0, stream>>>(pred_cls, pred_resp, pred_bb,
                                                              tgt_box, tix, tiy, tib, tlab, ws);

    finalize_kernel<<<1, 1, 0, stream>>>(ws, out);
}

// Round 2
// 353.803 us; speedup vs baseline: 1.3910x; 1.3910x over previous
//
#include <hip/hip_runtime.h>
#include <math.h>

#define Bn 64
#define An 5
#define Cn 80
#define Hn 52
#define Wn 52
#define Tn 32
#define HWn (Hn * Wn)

#define NB_CELL 1024   // cell_kernel blocks (grid-stride)
#define NB_TGT  512    // target_kernel blocks (4 waves = 4 targets each; 512*4 = 2048 targets)

// ws layout (doubles), all slots written unconditionally every launch (no memset needed):
//   [0 .. NB_CELL)                    : per-block cell partials (neg softplus sum)
//   [NB_CELL + k*NB_TGT .. +NB_TGT)   : per-block target partials, k = 0..4
//     k: 0=pos, 1=neg_corr, 2=cls, 3=xy, 4=wh

__device__ __forceinline__ float softplusf_(float x) {
    return fmaxf(x, 0.f) + log1pf(expf(-fabsf(x)));   // stable softplus
}

__device__ __forceinline__ float sigmoidf_(float x) {
    return 1.f / (1.f + expf(-x));
}

__device__ __forceinline__ float iou_cell(float pb0, float pb1, float pw, float ph,
                                          int h, int w,
                                          float gx1, float gy1, float gx2, float gy2,
                                          float tarea) {
    float px1 = sigmoidf_(pb0) + (float)w - pw * 0.5f;
    float py1 = sigmoidf_(pb1) + (float)h - ph * 0.5f;
    float px2 = px1 + pw, py2 = py1 + ph;
    float dx = fmaxf(fminf(px2, gx2) - fmaxf(px1, gx1), 0.f);
    float dy = fmaxf(fminf(py2, gy2) - fmaxf(py1, gy1), 0.f);
    float inter = dx * dy;
    return inter / (pw * ph + tarea - inter);
}

__global__ void cell_kernel(const float* __restrict__ pred_resp,
                            const float* __restrict__ pred_bb,
                            const float* __restrict__ tgt_box,
                            const int* __restrict__ tix,
                            const int* __restrict__ tiy,
                            double* __restrict__ cell_part) {
    float acc = 0.f;
    const int total = Bn * An * HWn;
    for (int idx = blockIdx.x * blockDim.x + threadIdx.x; idx < total;
         idx += blockDim.x * NB_CELL) {
        int b = idx / (An * HWn);
        int rem = idx - b * (An * HWn);
        int a = rem / HWn;
        int hw = rem - a * HWn;
        int h = hw / Wn;
        int w = hw - h * Wn;
        // neg_mask uses iou vs target T-1 of batch b only
        int tb = b * Tn + (Tn - 1);
        float tx = tgt_box[tb * 4 + 0], ty = tgt_box[tb * 4 + 1];
        float tw = tgt_box[tb * 4 + 2], th = tgt_box[tb * 4 + 3];
        float cx = tx + (float)tix[tb];
        float cy = ty + (float)tiy[tb];
        float gx1 = cx - tw * 0.5f, gy1 = cy - th * 0.5f;
        float gx2 = gx1 + tw, gy2 = gy1 + th;
        const float* pbb = pred_bb + ((size_t)(b * An + a) * 4) * HWn + hw;
        float pb0 = pbb[0];
        float pb1 = pbb[HWn];
        float pw  = pbb[2 * HWn];
        float ph  = pbb[3 * HWn];
        float iou = iou_cell(pb0, pb1, pw, ph, h, w, gx1, gy1, gx2, gy2, tw * th);
        if (iou < 0.6f) acc += softplusf_(pred_resp[idx]);  // off-target bce = softplus
    }
    // block reduction (blockDim.x == 256): wave shuffle then LDS
    for (int off = 32; off > 0; off >>= 1) acc += __shfl_down(acc, off);
    __shared__ float s[4];
    int lane = threadIdx.x & 63, wid = threadIdx.x >> 6;
    if (lane == 0) s[wid] = acc;
    __syncthreads();
    if (threadIdx.x == 0) {
        cell_part[blockIdx.x] = (double)(s[0] + s[1] + s[2] + s[3]);
    }
}

__global__ void target_kernel(const float* __restrict__ pred_cls,
                              const float* __restrict__ pred_resp,
                              const float* __restrict__ pred_bb,
                              const float* __restrict__ tgt_box,
                              const int* __restrict__ tix,
                              const int* __restrict__ tiy,
                              const int* __restrict__ tib,
                              const int* __restrict__ tlab,
                              double* __restrict__ tgt_part) {
    int wid = threadIdx.x >> 6;                 // wave in block, 0..3
    int lane = threadIdx.x & 63;
    int gwave = blockIdx.x * 4 + wid;           // target index, 0..2047
    int b = gwave / Tn;
    int t = gwave - b * Tn;
    int tb = b * Tn + t;
    int abox = tib[tb];
    int y = tiy[tb];
    int x = tix[tb];
    int label = tlab[tb];
    float tx = tgt_box[tb * 4 + 0], ty = tgt_box[tb * 4 + 1];
    float tw = tgt_box[tb * 4 + 2], th = tgt_box[tb * 4 + 3];

    // ---- class cross-entropy over Cn=80 logits, one wave ----
    const float* cl = pred_cls + ((size_t)b * (An * Cn) + (size_t)abox * Cn) * HWn + (size_t)y * Wn + x;
    float l0 = cl[(size_t)lane * HWn];
    float l1 = (lane < Cn - 64) ? cl[(size_t)(lane + 64) * HWn] : -INFINITY;
    float m = fmaxf(l0, l1);
    for (int off = 32; off > 0; off >>= 1) m = fmaxf(m, __shfl_xor(m, off));
    float se = expf(l0 - m) + ((lane < Cn - 64) ? expf(l1 - m) : 0.f);
    for (int off = 32; off > 0; off >>= 1) se += __shfl_xor(se, off);
    float lsel = (label < 64) ? __shfl(l0, label) : __shfl(l1, label - 64);
    float loss_cls = m + logf(se) - lsel;

    __shared__ float sm[4][5];
    if (lane == 0) {
        int hw = y * Wn + x;
        const float* pbb = pred_bb + ((size_t)(b * An + abox) * 4) * HWn + hw;
        float pb0 = pbb[0];
        float pb1 = pbb[HWn];
        float pw  = pbb[2 * HWn];
        float ph  = pbb[3 * HWn];
        float r = pred_resp[(size_t)(b * An + abox) * HWn + hw];
        float sp_r = softplusf_(r);

        // iou vs own target box -> gt_response at this (unique) cell
        float cx = tx + (float)x, cy = ty + (float)y;
        float gx1 = cx - tw * 0.5f, gy1 = cy - th * 0.5f;
        float gx2 = gx1 + tw, gy2 = gy1 + th;
        float iou_sel = iou_cell(pb0, pb1, pw, ph, y, x, gx1, gy1, gx2, gy2, tw * th);
        float pos = sp_r - r * iou_sel;

        // iou vs target T-1 (same value cell_kernel used) -> neg-sum correction
        int tb31 = b * Tn + (Tn - 1);
        float t31x = tgt_box[tb31 * 4 + 0], t31y = tgt_box[tb31 * 4 + 1];
        float t31w = tgt_box[tb31 * 4 + 2], t31h = tgt_box[tb31 * 4 + 3];
        float c31x = t31x + (float)tix[tb31];
        float c31y = t31y + (float)tiy[tb31];
        float g1x = c31x - t31w * 0.5f, g1y = c31y - t31h * 0.5f;
        float g2x = g1x + t31w, g2y = g1y + t31h;
        float iou31 = iou_cell(pb0, pb1, pw, ph, y, x, g1x, g1y, g2x, g2y, t31w * t31h);
        float negcorr = (iou31 < 0.6f) ? sp_r : 0.f;

        float lxy = (softplusf_(pb0) - pb0 * tx) + (softplusf_(pb1) - pb1 * ty);
        float lwh = (pw - tw) * (pw - tw) + (ph - th) * (ph - th);

        sm[wid][0] = pos;
        sm[wid][1] = negcorr;
        sm[wid][2] = loss_cls;
        sm[wid][3] = lxy;
        sm[wid][4] = lwh;
    }
    __syncthreads();
    if (threadIdx.x < 5) {
        int k = threadIdx.x;
        tgt_part[(size_t)k * NB_TGT + blockIdx.x] =
            (double)sm[0][k] + (double)sm[1][k] + (double)sm[2][k] + (double)sm[3][k];
    }
}

__global__ void finalize_kernel(const double* __restrict__ ws, float* __restrict__ out) {
    int lane = threadIdx.x;  // 64 threads, one wave
    const double* cell_part = ws;
    const double* tgt_part = ws + NB_CELL;

    double c = 0.0;
    for (int i = lane; i < NB_CELL; i += 64) c += cell_part[i];
    double tk[5];
    for (int k = 0; k < 5; ++k) {
        double v = 0.0;
        for (int i = lane; i < NB_TGT; i += 64) v += tgt_part[(size_t)k * NB_TGT + i];
        tk[k] = v;
    }
    for (int off = 32; off > 0; off >>= 1) {
        c += __shfl_down(c, off);
        for (int k = 0; k < 5; ++k) tk[k] += __shfl_down(tk[k], off);
    }
    if (lane == 0) {
        out[0] = (float)(tk[0] / Bn);
        out[1] = (float)(0.5 * (c - tk[1]) / Bn);   // L_NOOBJ * (neg_all - pos_cells_counted)
        out[2] = (float)(tk[2] / Bn);
        out[3] = (float)(tk[3] / Bn);
        out[4] = (float)(5.0 * tk[4] / Bn);         // L_COORD
    }
}

extern "C" void kernel_launch(void* const* d_in, const int* in_sizes, int n_in,
                              void* d_out, int out_size, void* d_ws, size_t ws_size,
                              hipStream_t stream) {
    const float* pred_cls  = (const float*)d_in[0];
    const float* pred_resp = (const float*)d_in[1];
    const float* pred_bb   = (const float*)d_in[2];
    const float* tgt_box   = (const float*)d_in[3];
    const int*   tix       = (const int*)d_in[4];
    const int*   tiy       = (const int*)d_in[5];
    const int*   tib       = (const int*)d_in[6];
    const int*   tlab      = (const int*)d_in[7];
    double* ws = (double*)d_ws;
    float* out = (float*)d_out;

    cell_kernel<<<NB_CELL, 256, 0, stream>>>(pred_resp, pred_bb, tgt_box, tix, tiy, ws);
    target_kernel<<<NB_TGT, 256, 0, stream>>>(pred_cls, pred_resp, pred_bb,
                                              tgt_box, tix, tiy, tib, tlab, ws + NB_CELL);
    finalize_kernel<<<1, 64, 0, stream>>>(ws, out);
}

// Round 3
// 341.366 us; speedup vs baseline: 1.4417x; 1.0364x over previous
//
#include <hip/hip_runtime.h>
#include <math.h>

#define Bn 64
#define An 5
#define Cn 80
#define Hn 52
#define Wn 52
#define Tn 32
#define HWn (Hn * Wn)

#define NB_TGT  512                 // target-role blocks: 4 waves = 4 targets each -> 2048 targets
#define NB_CELL 845                 // cell-role blocks: 845*256 threads * 4 cells = 865,280 = Bn*An*HWn exactly
#define NB_TOT  (NB_TGT + NB_CELL)

// ws layout (doubles), every slot written unconditionally each launch (no memset needed):
//   [0 .. NB_CELL)                      : per-block cell partials (softplus sum over neg cells)
//   [NB_CELL + k*NB_TGT .. +NB_TGT)     : per-block target partials, k: 0=pos,1=neg_corr,2=cls,3=xy,4=wh

__device__ __forceinline__ float softplusf_(float x) {
    return fmaxf(x, 0.f) + log1pf(expf(-fabsf(x)));   // stable softplus
}

__device__ __forceinline__ float sigmoidf_(float x) {
    return 1.f / (1.f + expf(-x));
}

__device__ __forceinline__ float iou_cell(float pb0, float pb1, float pw, float ph,
                                          int h, int w,
                                          float gx1, float gy1, float gx2, float gy2,
                                          float tarea) {
    float px1 = sigmoidf_(pb0) + (float)w - pw * 0.5f;
    float py1 = sigmoidf_(pb1) + (float)h - ph * 0.5f;
    float px2 = px1 + pw, py2 = py1 + ph;
    float dx = fmaxf(fminf(px2, gx2) - fmaxf(px1, gx1), 0.f);
    float dy = fmaxf(fminf(py2, gy2) - fmaxf(py1, gy1), 0.f);
    float inter = dx * dy;
    return inter / (pw * ph + tarea - inter);
}

__global__ void fused_kernel(const float* __restrict__ pred_cls,
                             const float* __restrict__ pred_resp,
                             const float* __restrict__ pred_bb,
                             const float* __restrict__ tgt_box,
                             const int* __restrict__ tix,
                             const int* __restrict__ tiy,
                             const int* __restrict__ tib,
                             const int* __restrict__ tlab,
                             double* __restrict__ ws) {
    int wid = threadIdx.x >> 6;
    int lane = threadIdx.x & 63;

    if (blockIdx.x < NB_TGT) {
        // ------------- target role: one wave per target -------------
        int gwave = blockIdx.x * 4 + wid;       // 0..2047
        int b = gwave / Tn;
        int t = gwave - b * Tn;
        int tb = b * Tn + t;
        int abox = tib[tb];
        int y = tiy[tb];
        int x = tix[tb];
        int label = tlab[tb];
        float tx = tgt_box[tb * 4 + 0], ty = tgt_box[tb * 4 + 1];
        float tw = tgt_box[tb * 4 + 2], th = tgt_box[tb * 4 + 3];

        // class cross-entropy over Cn=80 logits (strided gather, one wave)
        const float* cl = pred_cls + ((size_t)b * (An * Cn) + (size_t)abox * Cn) * HWn + (size_t)y * Wn + x;
        float l0 = cl[(size_t)lane * HWn];
        float l1 = (lane < Cn - 64) ? cl[(size_t)(lane + 64) * HWn] : -INFINITY;
        float m = fmaxf(l0, l1);
        for (int off = 32; off > 0; off >>= 1) m = fmaxf(m, __shfl_xor(m, off));
        float se = expf(l0 - m) + ((lane < Cn - 64) ? expf(l1 - m) : 0.f);
        for (int off = 32; off > 0; off >>= 1) se += __shfl_xor(se, off);
        float lsel = (label < 64) ? __shfl(l0, label) : __shfl(l1, label - 64);
        float loss_cls = m + logf(se) - lsel;

        __shared__ float sm[4][5];
        if (lane == 0) {
            int hw = y * Wn + x;
            const float* pbb = pred_bb + ((size_t)(b * An + abox) * 4) * HWn + hw;
            float pb0 = pbb[0];
            float pb1 = pbb[HWn];
            float pw  = pbb[2 * HWn];
            float ph  = pbb[3 * HWn];
            float r = pred_resp[(size_t)(b * An + abox) * HWn + hw];
            float sp_r = softplusf_(r);

            // iou vs own target box -> gt_response at this (unique) cell
            float cx = tx + (float)x, cy = ty + (float)y;
            float gx1 = cx - tw * 0.5f, gy1 = cy - th * 0.5f;
            float gx2 = gx1 + tw, gy2 = gy1 + th;
            float iou_sel = iou_cell(pb0, pb1, pw, ph, y, x, gx1, gy1, gx2, gy2, tw * th);
            float pos = sp_r - r * iou_sel;

            // iou vs target T-1 (bit-identical to cell-role expression) -> neg-sum correction
            int tb31 = b * Tn + (Tn - 1);
            float t31x = tgt_box[tb31 * 4 + 0], t31y = tgt_box[tb31 * 4 + 1];
            float t31w = tgt_box[tb31 * 4 + 2], t31h = tgt_box[tb31 * 4 + 3];
            float c31x = t31x + (float)tix[tb31];
            float c31y = t31y + (float)tiy[tb31];
            float g1x = c31x - t31w * 0.5f, g1y = c31y - t31h * 0.5f;
            float g2x = g1x + t31w, g2y = g1y + t31h;
            float iou31 = iou_cell(pb0, pb1, pw, ph, y, x, g1x, g1y, g2x, g2y, t31w * t31h);
            float negcorr = (iou31 < 0.6f) ? sp_r : 0.f;

            float lxy = (softplusf_(pb0) - pb0 * tx) + (softplusf_(pb1) - pb1 * ty);
            float lwh = (pw - tw) * (pw - tw) + (ph - th) * (ph - th);

            sm[wid][0] = pos;
            sm[wid][1] = negcorr;
            sm[wid][2] = loss_cls;
            sm[wid][3] = lxy;
            sm[wid][4] = lwh;
        }
        __syncthreads();
        if (threadIdx.x < 5) {
            int k = threadIdx.x;
            ws[NB_CELL + (size_t)k * NB_TGT + blockIdx.x] =
                (double)sm[0][k] + (double)sm[1][k] + (double)sm[2][k] + (double)sm[3][k];
        }
    } else {
        // ------------- cell role: 4 cells per thread via float4 -------------
        int cb = blockIdx.x - NB_TGT;                       // 0..844
        int g = cb * 256 + threadIdx.x;                     // 0..216319, exactly covers all cells
        int idx0 = g * 4;
        int b = idx0 / (An * HWn);
        int rem = idx0 - b * (An * HWn);
        int a = rem / HWn;
        int hw = rem - a * HWn;
        int h = hw / Wn;
        int w0 = hw - h * Wn;                               // 4 | Wn so the 4 cells share row h

        // target T-1 of batch b (neg_mask uses iou[:, -1] only)
        int tb = b * Tn + (Tn - 1);
        float tx = tgt_box[tb * 4 + 0], ty = tgt_box[tb * 4 + 1];
        float tw = tgt_box[tb * 4 + 2], th = tgt_box[tb * 4 + 3];
        float cx = tx + (float)tix[tb];
        float cy = ty + (float)tiy[tb];
        float gx1 = cx - tw * 0.5f, gy1 = cy - th * 0.5f;
        float gx2 = gx1 + tw, gy2 = gy1 + th;
        float tarea = tw * th;

        const float* plane = pred_bb + ((size_t)(b * An + a) * 4) * HWn + hw;
        float4 v0 = *(const float4*)(plane);
        float4 v1 = *(const float4*)(plane + HWn);
        float4 v2 = *(const float4*)(plane + 2 * HWn);
        float4 v3 = *(const float4*)(plane + 3 * HWn);
        float4 rr = *(const float4*)(pred_resp + (size_t)(b * An + a) * HWn + hw);

        float acc = 0.f;
        {
            float iou = iou_cell(v0.x, v1.x, v2.x, v3.x, h, w0 + 0, gx1, gy1, gx2, gy2, tarea);
            if (iou < 0.6f) acc += softplusf_(rr.x);
        }
        {
            float iou = iou_cell(v0.y, v1.y, v2.y, v3.y, h, w0 + 1, gx1, gy1, gx2, gy2, tarea);
            if (iou < 0.6f) acc += softplusf_(rr.y);
        }
        {
            float iou = iou_cell(v0.z, v1.z, v2.z, v3.z, h, w0 + 2, gx1, gy1, gx2, gy2, tarea);
            if (iou < 0.6f) acc += softplusf_(rr.z);
        }
        {
            float iou = iou_cell(v0.w, v1.w, v2.w, v3.w, h, w0 + 3, gx1, gy1, gx2, gy2, tarea);
            if (iou < 0.6f) acc += softplusf_(rr.w);
        }

        for (int off = 32; off > 0; off >>= 1) acc += __shfl_down(acc, off);
        __shared__ float s[4];
        if (lane == 0) s[wid] = acc;
        __syncthreads();
        if (threadIdx.x == 0) {
            ws[cb] = (double)(s[0] + s[1] + s[2] + s[3]);
        }
    }
}

__global__ void finalize_kernel(const double* __restrict__ ws, float* __restrict__ out) {
    int tid = threadIdx.x;   // 256 threads
    int lane = tid & 63, wid = tid >> 6;
    const double* cell_part = ws;
    const double* tgt_part = ws + NB_CELL;

    double c = 0.0;
    for (int i = tid; i < NB_CELL; i += 256) c += cell_part[i];
    double tk[5];
    for (int k = 0; k < 5; ++k) {
        double v = 0.0;
        for (int i = tid; i < NB_TGT; i += 256) v += tgt_part[(size_t)k * NB_TGT + i];
        tk[k] = v;
    }
    for (int off = 32; off > 0; off >>= 1) {
        c += __shfl_down(c, off);
        for (int k = 0; k < 5; ++k) tk[k] += __shfl_down(tk[k], off);
    }
    __shared__ double sd[4][6];
    if (lane == 0) {
        sd[wid][0] = c;
        for (int k = 0; k < 5; ++k) sd[wid][k + 1] = tk[k];
    }
    __syncthreads();
    if (tid == 0) {
        double cc = sd[0][0] + sd[1][0] + sd[2][0] + sd[3][0];
        double t0 = sd[0][1] + sd[1][1] + sd[2][1] + sd[3][1];
        double t1 = sd[0][2] + sd[1][2] + sd[2][2] + sd[3][2];
        double t2 = sd[0][3] + sd[1][3] + sd[2][3] + sd[3][3];
        double t3 = sd[0][4] + sd[1][4] + sd[2][4] + sd[3][4];
        double t4 = sd[0][5] + sd[1][5] + sd[2][5] + sd[3][5];
        out[0] = (float)(t0 / Bn);
        out[1] = (float)(0.5 * (cc - t1) / Bn);   // L_NOOBJ * (neg_all - pos_cells_counted)
        out[2] = (float)(t2 / Bn);
        out[3] = (float)(t3 / Bn);
        out[4] = (float)(5.0 * t4 / Bn);          // L_COORD
    }
}

extern "C" void kernel_launch(void* const* d_in, const int* in_sizes, int n_in,
                              void* d_out, int out_size, void* d_ws, size_t ws_size,
                              hipStream_t stream) {
    const float* pred_cls  = (const float*)d_in[0];
    const float* pred_resp = (const float*)d_in[1];
    const float* pred_bb   = (const float*)d_in[2];
    const float* tgt_box   = (const float*)d_in[3];
    const int*   tix       = (const int*)d_in[4];
    const int*   tiy       = (const int*)d_in[5];
    const int*   tib       = (const int*)d_in[6];
    const int*   tlab      = (const int*)d_in[7];
    double* ws = (double*)d_ws;
    float* out = (float*)d_out;

    fused_kernel<<<NB_TOT, 256, 0, stream>>>(pred_cls, pred_resp, pred_bb,
                                             tgt_box, tix, tiy, tib, tlab, ws);
    finalize_kernel<<<1, 256, 0, stream>>>(ws, out);
}